// Round 2
// baseline (173.745 us; speedup 1.0000x reference)
//
#include <hip/hip_runtime.h>

#define NV 32          // float4 chunks per row (128 floats)
#define HALFB 0.5f
#define CAPB  0.1f

__device__ __forceinline__ float clip05(float z) {
    return fminf(fmaxf(z, -HALFB), HALFB);
}

// One thread owns one full row of 128 elements in registers.
// No cross-lane operations anywhere: all reductions are per-thread scalar.
__global__ __launch_bounds__(256, 2) void proj_kernel(
    const float* __restrict__ x, float* __restrict__ out, int nrows)
{
    const int row = blockIdx.x * blockDim.x + threadIdx.x;
    if (row >= nrows) return;

    const float4* __restrict__ px = reinterpret_cast<const float4*>(x) + (size_t)row * NV;
    float4*       __restrict__ po = reinterpret_cast<float4*>(out)     + (size_t)row * NV;

    float4 v[NV];
    float s0 = 0.f, vmin = 3.0e38f, vmax = -3.0e38f;
    #pragma unroll
    for (int j = 0; j < NV; ++j) {
        v[j] = px[j];
        const float a0 = v[j].x, a1 = v[j].y, a2 = v[j].z, a3 = v[j].w;
        s0 += clip05(a0) + clip05(a1) + clip05(a2) + clip05(a3);
        vmin = fminf(vmin, fminf(fminf(a0, a1), fminf(a2, a3)));
        vmax = fmaxf(vmax, fmaxf(fmaxf(a0, a1), fmaxf(a2, a3)));
    }
    const float t = fminf(fmaxf(s0, -CAPB), CAPB);

    // g(0) = s0; n_act(0)
    float g = s0;
    int na = 0;
    #pragma unroll
    for (int j = 0; j < NV; ++j) {
        na += (fabsf(v[j].x) < HALFB) + (fabsf(v[j].y) < HALFB)
            + (fabsf(v[j].z) < HALFB) + (fabsf(v[j].w) < HALFB);
    }

    // Safeguarded Newton on g(lam) = t  (g piecewise-linear, decreasing).
    // Invariant: root in (lo, hi]. Newton step == reference's closed form
    // over the current active set. Bisection fallback guarantees progress.
    float lo = vmin - (HALFB + CAPB);
    float hi = vmax + (HALFB + CAPB);
    float lam = 0.f;
    for (int it = 0; it < 32; ++it) {
        if (g > t) lo = lam; else hi = lam;
        float ln;
        if (na > 0) {
            ln = lam + (g - t) / (float)na;
            if (!(ln > lo && ln <= hi)) ln = 0.5f * (lo + hi);
        } else {
            ln = 0.5f * (lo + hi);
        }
        if (ln == lam) break;
        lam = ln;

        g = 0.f; na = 0;
        #pragma unroll
        for (int j = 0; j < NV; ++j) {
            const float z0 = v[j].x - lam, z1 = v[j].y - lam;
            const float z2 = v[j].z - lam, z3 = v[j].w - lam;
            g  += clip05(z0) + clip05(z1) + clip05(z2) + clip05(z3);
            na += (fabsf(z0) < HALFB) + (fabsf(z1) < HALFB)
                + (fabsf(z2) < HALFB) + (fabsf(z3) < HALFB);
        }
    }

    // Final closed-form recompute over the active set at lam — exactly the
    // reference's last step (exact implicit-gradient formula).
    float sum_act = 0.f;
    int n_act = 0, n_hi = 0, n_lo = 0;
    #pragma unroll
    for (int j = 0; j < NV; ++j) {
        const float a[4] = { v[j].x, v[j].y, v[j].z, v[j].w };
        #pragma unroll
        for (int k = 0; k < 4; ++k) {
            const float z = a[k] - lam;
            const bool act = (z > -HALFB) & (z < HALFB);
            sum_act += act ? a[k] : 0.f;
            n_act += act;
            n_hi  += (z >=  HALFB);
            n_lo  += (z <= -HALFB);
        }
    }
    const float lam_f = (n_act > 0)
        ? (sum_act + HALFB * (float)(n_hi - n_lo) - t) / (float)n_act
        : lam;

    #pragma unroll
    for (int j = 0; j < NV; ++j) {
        po[j] = make_float4(clip05(v[j].x - lam_f), clip05(v[j].y - lam_f),
                            clip05(v[j].z - lam_f), clip05(v[j].w - lam_f));
    }
}

extern "C" void kernel_launch(void* const* d_in, const int* in_sizes, int n_in,
                              void* d_out, int out_size, void* d_ws, size_t ws_size,
                              hipStream_t stream) {
    const float* x = (const float*)d_in[0];
    float* out     = (float*)d_out;
    const int nrows = out_size / 128;   // 262144
    const int block = 256;
    const int grid  = (nrows + block - 1) / block;   // 1024
    hipLaunchKernelGGL(proj_kernel, dim3(grid), dim3(block), 0, stream, x, out, nrows);
}

// Round 3
// 95.501 us; speedup vs baseline: 1.8193x; 1.8193x over previous
//
#include <hip/hip_runtime.h>

#define NV 32          // float4 chunks per row (128 floats)
#define HALFB 0.5f
#define CAPB  0.1f

__device__ __forceinline__ float clip05(float z) {
    return fminf(fmaxf(z, -HALFB), HALFB);   // compiles to v_med3_f32
}

// One thread owns one full row of 128 elements in registers (no cross-lane ops).
// Solver: safeguarded Newton with residual early-exit + closed-form final lam.
// Epilogue: lam via LDS, block-cooperative coalesced re-read/write of the tile.
__global__ __launch_bounds__(256, 2) void proj_kernel(
    const float* __restrict__ x, float* __restrict__ out, int nrows)
{
    const int tid  = threadIdx.x;
    const int row0 = blockIdx.x << 8;      // 256 rows per block
    const int row  = row0 + tid;

    __shared__ float lamS[256];

    float lam_f = 0.0f;

    if (row < nrows) {
        const float4* __restrict__ px =
            reinterpret_cast<const float4*>(x) + (size_t)row * NV;

        float4 v[NV];
        float s0 = 0.f, vmin = 3.0e38f, vmax = -3.0e38f, naf = 0.f;
        #pragma unroll
        for (int j = 0; j < NV; ++j) {
            v[j] = px[j];
            const float a0 = v[j].x, a1 = v[j].y, a2 = v[j].z, a3 = v[j].w;
            s0 += clip05(a0) + clip05(a1) + clip05(a2) + clip05(a3);
            vmin = fminf(vmin, fminf(fminf(a0, a1), fminf(a2, a3)));
            vmax = fmaxf(vmax, fmaxf(fmaxf(a0, a1), fmaxf(a2, a3)));
            naf += ((fabsf(a0) < HALFB) ? 1.f : 0.f) + ((fabsf(a1) < HALFB) ? 1.f : 0.f)
                 + ((fabsf(a2) < HALFB) ? 1.f : 0.f) + ((fabsf(a3) < HALFB) ? 1.f : 0.f);
        }
        const float t = fminf(fmaxf(s0, -CAPB), CAPB);

        float g   = s0;
        float lo  = vmin - (HALFB + CAPB);
        float hi  = vmax + (HALFB + CAPB);
        float lam = 0.f;

        for (int it = 0; it < 24; ++it) {
            // Residual exit: closed-form recompute below heals a residual of
            // delta to output error ~delta, so 2e-5 is plenty (thr = 1e-2).
            if (fabsf(g - t) <= 2e-5f) break;
            if (g > t) lo = lam; else hi = lam;
            float ln;
            if (naf > 0.f) {
                ln = lam + (g - t) * __builtin_amdgcn_rcpf(naf);
                if (!(ln > lo && ln < hi)) ln = 0.5f * (lo + hi);
            } else {
                ln = 0.5f * (lo + hi);
            }
            if (ln == lam) break;
            lam = ln;

            g = 0.f; naf = 0.f;
            #pragma unroll
            for (int j = 0; j < NV; ++j) {
                const float z0 = v[j].x - lam, z1 = v[j].y - lam;
                const float z2 = v[j].z - lam, z3 = v[j].w - lam;
                g += clip05(z0) + clip05(z1) + clip05(z2) + clip05(z3);
                naf += ((fabsf(z0) < HALFB) ? 1.f : 0.f) + ((fabsf(z1) < HALFB) ? 1.f : 0.f)
                     + ((fabsf(z2) < HALFB) ? 1.f : 0.f) + ((fabsf(z3) < HALFB) ? 1.f : 0.f);
            }
        }

        // Exact closed form over the active set at lam (reference's last step).
        float sa = 0.f, nact = 0.f, nhml = 0.f;
        #pragma unroll
        for (int j = 0; j < NV; ++j) {
            const float a[4] = { v[j].x, v[j].y, v[j].z, v[j].w };
            #pragma unroll
            for (int k = 0; k < 4; ++k) {
                const float z = a[k] - lam;
                const bool act = fabsf(z) < HALFB;       // strict, matches ref
                sa   += act ? a[k] : 0.f;
                nact += act ? 1.f : 0.f;
                nhml += (z >= HALFB ? 1.f : 0.f) - (z <= -HALFB ? 1.f : 0.f);
            }
        }
        lam_f = (nact > 0.f) ? (sa + HALFB * nhml - t) / nact : lam;
    }

    lamS[tid] = lam_f;
    __syncthreads();

    // Coalesced epilogue: block tile = 256 rows x 32 float4; consecutive tid ->
    // consecutive float4 -> full 1KiB lines per wave store. x re-read hits L2/L3.
    const float4* __restrict__ pxb =
        reinterpret_cast<const float4*>(x) + (size_t)row0 * NV;
    float4* __restrict__ pob =
        reinterpret_cast<float4*>(out) + (size_t)row0 * NV;
    #pragma unroll
    for (int k = 0; k < NV; ++k) {
        const int idx = (k << 8) + tid;      // 0..8191 across the loop
        const int r   = idx >> 5;            // row-in-block (float4 col = idx&31)
        if (row0 + r < nrows) {
            const float  l = lamS[r];        // 2-address broadcast, no conflicts
            const float4 a = pxb[idx];
            pob[idx] = make_float4(clip05(a.x - l), clip05(a.y - l),
                                   clip05(a.z - l), clip05(a.w - l));
        }
    }
}

extern "C" void kernel_launch(void* const* d_in, const int* in_sizes, int n_in,
                              void* d_out, int out_size, void* d_ws, size_t ws_size,
                              hipStream_t stream) {
    const float* x = (const float*)d_in[0];
    float* out     = (float*)d_out;
    const int nrows = out_size / 128;            // 262144
    const int grid  = (nrows + 255) / 256;       // 1024
    hipLaunchKernelGGL(proj_kernel, dim3(grid), dim3(256), 0, stream, x, out, nrows);
}

// Round 4
// 61.845 us; speedup vs baseline: 2.8094x; 1.5442x over previous
//
#include <hip/hip_runtime.h>

#define HALFB 0.5f
#define CAPB  0.1f

__device__ __forceinline__ float clip05(float z) {
    return fminf(fmaxf(z, -HALFB), HALFB);   // v_med3_f32
}

// Reductions across the 4-lane group that owns one row (masks 1,2 stay in-group).
__device__ __forceinline__ float red4f(float v) {
    v += __shfl_xor(v, 1); v += __shfl_xor(v, 2); return v;
}
__device__ __forceinline__ int red4i(int v) {
    v += __shfl_xor(v, 1); v += __shfl_xor(v, 2); return v;
}
__device__ __forceinline__ float min4f(float v) {
    v = fminf(v, __shfl_xor(v, 1)); v = fminf(v, __shfl_xor(v, 2)); return v;
}
__device__ __forceinline__ float max4f(float v) {
    v = fmaxf(v, __shfl_xor(v, 1)); v = fmaxf(v, __shfl_xor(v, 2)); return v;
}

// 4 lanes per row, 32 elems (8 x float4) per lane, row data lives in VGPRs.
// Solver identical in semantics to the round-2/3 proven version:
// safeguarded Newton on g(lam)=t with residual exit, then one exact-division
// Newton step == reference's closed form over the active set.
__global__ __launch_bounds__(256, 4) void proj_kernel(
    const float* __restrict__ x, float* __restrict__ out, int nrows)
{
    const int lane = threadIdx.x & 63;
    const int wid  = (blockIdx.x << 2) | (threadIdx.x >> 6);   // wave id
    const int q    = lane & 3;                                  // quarter of row
    int row = (wid << 4) | (lane >> 2);                         // 16 rows / wave
    if (row >= nrows) row = nrows - 1;   // defensive; grid divides exactly

    const float4* __restrict__ px = (const float4*)x  + ((size_t)row << 5) + (q << 3);
    float4*       __restrict__ po = (float4*)out      + ((size_t)row << 5) + (q << 3);

    float4 v[8];
    float s0 = 0.f, vmn = 3.0e38f, vmx = -3.0e38f;
    int   nai = 0;
    #pragma unroll
    for (int j = 0; j < 8; ++j) {
        v[j] = px[j];
        const float a[4] = { v[j].x, v[j].y, v[j].z, v[j].w };
        #pragma unroll
        for (int k = 0; k < 4; ++k) {
            s0  += clip05(a[k]);
            nai += (fabsf(a[k]) < HALFB);
            vmn  = fminf(vmn, a[k]);
            vmx  = fmaxf(vmx, a[k]);
        }
    }
    s0  = red4f(s0);
    nai = red4i(nai);
    vmn = min4f(vmn);
    vmx = max4f(vmx);

    const float t = fminf(fmaxf(s0, -CAPB), CAPB);

    float g   = s0;
    float na  = (float)nai;
    float lo  = vmn - (HALFB + CAPB);
    float hi  = vmx + (HALFB + CAPB);
    float lam = 0.f;

    for (int it = 0; it < 20; ++it) {
        if (fabsf(g - t) <= 2e-5f) break;     // final division heals residual
        if (g > t) lo = lam; else hi = lam;   // g decreasing in lam
        float ln;
        if (na > 0.f) {
            ln = lam + (g - t) * __builtin_amdgcn_rcpf(na);
            if (!(ln > lo && ln < hi)) ln = 0.5f * (lo + hi);
        } else {
            ln = 0.5f * (lo + hi);
        }
        if (ln == lam) break;
        lam = ln;

        float gp = 0.f; int np = 0;
        #pragma unroll
        for (int j = 0; j < 8; ++j) {
            const float a[4] = { v[j].x, v[j].y, v[j].z, v[j].w };
            #pragma unroll
            for (int k = 0; k < 4; ++k) {
                const float z = a[k] - lam;
                gp += clip05(z);
                np += (fabsf(z) < HALFB);
            }
        }
        g  = red4f(gp);
        na = (float)red4i(np);
    }

    // Exact closed form (== reference): lam + (g - t)/n_act with true division.
    const float lam_f = (na > 0.f) ? lam + (g - t) / na : lam;

    #pragma unroll
    for (int j = 0; j < 8; ++j) {
        po[j] = make_float4(clip05(v[j].x - lam_f), clip05(v[j].y - lam_f),
                            clip05(v[j].z - lam_f), clip05(v[j].w - lam_f));
    }
}

extern "C" void kernel_launch(void* const* d_in, const int* in_sizes, int n_in,
                              void* d_out, int out_size, void* d_ws, size_t ws_size,
                              hipStream_t stream) {
    const float* x = (const float*)d_in[0];
    float* out     = (float*)d_out;
    const int nrows = out_size / 128;             // 262144
    const int grid  = (nrows + 63) / 64;          // 64 rows per 256-thread block
    hipLaunchKernelGGL(proj_kernel, dim3(grid), dim3(256), 0, stream, x, out, nrows);
}